// Round 11
// baseline (832.575 us; speedup 1.0000x reference)
//
#include <hip/hip_runtime.h>

#define S 4096
#define D 64
#define NB 16

typedef _Float16 half8 __attribute__((ext_vector_type(8)));
typedef _Float16 half2v __attribute__((ext_vector_type(2)));
typedef float f32x4 __attribute__((ext_vector_type(4)));
typedef int int4v __attribute__((ext_vector_type(4)));

// ---- Prepass A: Q (scaled by 1/8) and K -> fp16 ----
__global__ void cvt_qk(const float* __restrict__ Q, const float* __restrict__ K,
                       _Float16* __restrict__ Qh, _Float16* __restrict__ Kh, int n) {
  int i = blockIdx.x * blockDim.x + threadIdx.x;
  int stride = gridDim.x * blockDim.x;
  for (; i < n; i += stride) {
    Qh[i] = (_Float16)(Q[i] * 0.125f);   // fold 1/TEMPERATURE into Q
    Kh[i] = (_Float16)(K[i]);
  }
}

// ---- Prepass B: V -> fp16 transposed Vt[b][d][s] ----
__global__ void cvt_vt(const float* __restrict__ V, _Float16* __restrict__ Vt) {
  __shared__ float tile[64][65];
  int b = blockIdx.x >> 6;
  int s0 = (blockIdx.x & 63) * 64;
  const float* vb = V + ((size_t)b * S) * D;
  for (int i = threadIdx.x; i < 64 * 64; i += 256) {
    int sl = i >> 6, d = i & 63;
    tile[sl][d] = vb[(size_t)(s0 + sl) * D + d];
  }
  __syncthreads();
  _Float16* vtb = Vt + ((size_t)b * D) * S;
  for (int i = threadIdx.x; i < 64 * 64; i += 256) {
    int dl = i >> 6, sl = i & 63;
    vtb[(size_t)dl * S + s0 + sl] = (_Float16)tile[sl][dl];
  }
}

// ---- Single fused attention: one wave owns one 16-query tile x ALL keys ----
// 512 blocks x 8 waves = 4096 q-tiles; grid = exactly 2 blocks/CU, one round.
// Sweep 1: QK^T(swapped)->exp->vsum (shfl reduce only) -> ls in register.
// Sweep 2: recompute (bitwise-identical) -> normalized f32 A-store + shfl-
// transpose PV -> direct per-wave X store. ZERO LDS, ZERO barriers, 128-iter
// steady-state loops, depth-1 K prefetch. All 8 waves scan the same K stream
// (intra-block L1 reuse). launch_bounds 2nd arg = blocks/CU on this hipcc:
// (512,2) -> 4 waves/SIMD -> 128-VGPR budget (R6 measured 120 at this shape).
__global__ __launch_bounds__(512, 2) void attn_all(
    const _Float16* __restrict__ Qh, const _Float16* __restrict__ Kh,
    const _Float16* __restrict__ Vt, float* __restrict__ X,
    float* __restrict__ Aout) {
  const int tid = threadIdx.x;
  const int w = tid >> 6;
  const int l = tid & 63;
  const int l15 = l & 15;
  const int lq = l >> 4;
  const int r4 = lq * 4;
  const int qt = blockIdx.x * 8 + w;     // q-tile id 0..4095
  const int b = qt >> 8;
  const int m0 = (qt & 255) * 16;

  const _Float16* qb = Qh + ((size_t)b * S + m0) * D;
  const _Float16* kb = Kh + ((size_t)b * S) * D;
  const _Float16* vtb = Vt + ((size_t)b * D) * S;

  half8 qf0 = *(const half8*)(qb + (size_t)l15 * D + lq * 8);
  half8 qf1 = *(const half8*)(qb + (size_t)l15 * D + 32 + lq * 8);

  const int srcA = (lq & 1) * 32 + l15;
  const int srcB = srcA + 16;
  const bool hi = (lq & 2) != 0;

  const _Float16* kp0 = kb + (size_t)l15 * D + lq * 8;   // key row l15, col lq*8
  const _Float16* vp0 = vtb + (size_t)l15 * S + lq * 8;

  // ---- sweep 1: row sums ----
  float vsum = 0.f;
  half8 kc0 = *(const half8*)(kp0);
  half8 kc1 = *(const half8*)(kp0 + 32);
#pragma unroll 1
  for (int s = 0; s < 128; ++s) {
    const _Float16* k1p = kp0 + (size_t)(s * 32 + 16) * D;
    half8 k10 = *(const half8*)(k1p);
    half8 k11 = *(const half8*)(k1p + 32);
    half8 kn0 = kc0, kn1 = kc1;
    if (s < 127) {
      const _Float16* knp = kp0 + (size_t)((s + 1) * 32) * D;
      kn0 = *(const half8*)(knp);
      kn1 = *(const half8*)(knp + 32);
    }
    f32x4 a0 = (f32x4){0.f, 0.f, 0.f, 0.f};
    a0 = __builtin_amdgcn_mfma_f32_16x16x32_f16(kc0, qf0, a0, 0, 0, 0);
    a0 = __builtin_amdgcn_mfma_f32_16x16x32_f16(kc1, qf1, a0, 0, 0, 0);
    vsum += (__expf(a0[0]) + __expf(a0[1])) + (__expf(a0[2]) + __expf(a0[3]));
    f32x4 a1 = (f32x4){0.f, 0.f, 0.f, 0.f};
    a1 = __builtin_amdgcn_mfma_f32_16x16x32_f16(k10, qf0, a1, 0, 0, 0);
    a1 = __builtin_amdgcn_mfma_f32_16x16x32_f16(k11, qf1, a1, 0, 0, 0);
    vsum += (__expf(a1[0]) + __expf(a1[1])) + (__expf(a1[2]) + __expf(a1[3]));
    kc0 = kn0; kc1 = kn1;
  }
  // reduce over the 4 lq-lanes sharing query l15 (in-wave, no LDS)
  vsum += __shfl_xor(vsum, 16, 64);
  vsum += __shfl_xor(vsum, 32, 64);
  const float ls = __logf(vsum);

  // ---- sweep 2: normalized A stores + PV ----
  f32x4 xacc[4];
#pragma unroll
  for (int fd = 0; fd < 4; ++fd) xacc[fd] = (f32x4){0.f, 0.f, 0.f, 0.f};
  float* arow = Aout + ((size_t)(b * S + m0 + l15)) * S + r4;

  kc0 = *(const half8*)(kp0);
  kc1 = *(const half8*)(kp0 + 32);
#pragma unroll 1
  for (int s = 0; s < 128; ++s) {
    const _Float16* vs = vp0 + s * 32;
    half8 bf0 = *(const half8*)(vs);
    half8 bf1 = *(const half8*)(vs + 16 * S);
    half8 bf2 = *(const half8*)(vs + 32 * S);
    half8 bf3 = *(const half8*)(vs + 48 * S);
    const _Float16* k1p = kp0 + (size_t)(s * 32 + 16) * D;
    half8 k10 = *(const half8*)(k1p);
    half8 k11 = *(const half8*)(k1p + 32);
    half8 kn0 = kc0, kn1 = kc1;
    if (s < 127) {
      const _Float16* knp = kp0 + (size_t)((s + 1) * 32) * D;
      kn0 = *(const half8*)(knp);
      kn1 = *(const half8*)(knp + 32);
    }
    // t0: keys s*32 + (0..15)
    f32x4 a0 = (f32x4){0.f, 0.f, 0.f, 0.f};
    a0 = __builtin_amdgcn_mfma_f32_16x16x32_f16(kc0, qf0, a0, 0, 0, 0);
    a0 = __builtin_amdgcn_mfma_f32_16x16x32_f16(kc1, qf1, a0, 0, 0, 0);
    f32x4 o0;
#pragma unroll
    for (int j = 0; j < 4; ++j) o0[j] = __expf(a0[j] - ls);
    *(f32x4*)(arow + s * 32) = o0;
    half2v h01 = {(_Float16)o0[0], (_Float16)o0[1]};
    half2v h23 = {(_Float16)o0[2], (_Float16)o0[3]};
    int dw0x = __builtin_bit_cast(int, h01);
    int dw0y = __builtin_bit_cast(int, h23);
    // t1: keys s*32 + 16 + (0..15)
    f32x4 a1 = (f32x4){0.f, 0.f, 0.f, 0.f};
    a1 = __builtin_amdgcn_mfma_f32_16x16x32_f16(k10, qf0, a1, 0, 0, 0);
    a1 = __builtin_amdgcn_mfma_f32_16x16x32_f16(k11, qf1, a1, 0, 0, 0);
    f32x4 o1;
#pragma unroll
    for (int j = 0; j < 4; ++j) o1[j] = __expf(a1[j] - ls);
    *(f32x4*)(arow + s * 32 + 16) = o1;
    half2v g01 = {(_Float16)o1[0], (_Float16)o1[1]};
    half2v g23 = {(_Float16)o1[2], (_Float16)o1[3]};
    int dw1x = __builtin_bit_cast(int, g01);
    int dw1y = __builtin_bit_cast(int, g23);
    // shfl transpose -> PV A-frag (proven R8-R10)
    int yA0 = __shfl(dw0x, srcA, 64), yA1 = __shfl(dw0y, srcA, 64);
    int yB0 = __shfl(dw0x, srcB, 64), yB1 = __shfl(dw0y, srcB, 64);
    int xA0 = __shfl(dw1x, srcA, 64), xA1 = __shfl(dw1y, srcA, 64);
    int xB0 = __shfl(dw1x, srcB, 64), xB1 = __shfl(dw1y, srcB, 64);
    int4v ai = {hi ? xA0 : yA0, hi ? xA1 : yA1, hi ? xB0 : yB0, hi ? xB1 : yB1};
    half8 af = __builtin_bit_cast(half8, ai);
    xacc[0] = __builtin_amdgcn_mfma_f32_16x16x32_f16(af, bf0, xacc[0], 0, 0, 0);
    xacc[1] = __builtin_amdgcn_mfma_f32_16x16x32_f16(af, bf1, xacc[1], 0, 0, 0);
    xacc[2] = __builtin_amdgcn_mfma_f32_16x16x32_f16(af, bf2, xacc[2], 0, 0, 0);
    xacc[3] = __builtin_amdgcn_mfma_f32_16x16x32_f16(af, bf3, xacc[3], 0, 0, 0);
    kc0 = kn0; kc1 = kn1;
  }

  // ---- direct per-wave X store (P was normalized; no reduction needed) ----
  float* xb = X + ((size_t)b * S + m0) * D;
#pragma unroll
  for (int fd = 0; fd < 4; ++fd)
#pragma unroll
    for (int j = 0; j < 4; ++j)
      xb[(size_t)(r4 + j) * D + fd * 16 + l15] = xacc[fd][j];
}

extern "C" void kernel_launch(void* const* d_in, const int* in_sizes, int n_in,
                              void* d_out, int out_size, void* d_ws, size_t ws_size,
                              hipStream_t stream) {
  const float* Q = (const float*)d_in[0];
  const float* K = (const float*)d_in[1];
  const float* V = (const float*)d_in[2];
  float* X = (float*)d_out;                       // [16,4096,64]
  float* A = X + (size_t)NB * S * D;              // [16,4096,4096]
  _Float16* Qh = (_Float16*)d_ws;
  _Float16* Kh = Qh + (size_t)NB * S * D;
  _Float16* Vt = Kh + (size_t)NB * S * D;
  int n = NB * S * D;
  cvt_qk<<<2048, 256, 0, stream>>>(Q, K, Qh, Kh, n);
  cvt_vt<<<NB * 64, 256, 0, stream>>>(V, Vt);
  attn_all<<<512, 512, 0, stream>>>(Qh, Kh, Vt, X, A);
}